// Round 1
// baseline (52887.476 us; speedup 1.0000x reference)
//
#include <hip/hip_runtime.h>
#include <math.h>

// Problem constants
#define B   32
#define T   300
#define ENC 1024
#define H   512
#define A   256
#define CC  10
#define KK  100
#define KW  201     // 2K+1
#define V   10000
#define E   512
#define AO  512
#define TD  80
#define BOS 1
#define SCALING 2.0f

__device__ __forceinline__ float sigmoidf_(float x) { return 1.f / (1.f + expf(-x)); }

// ---------------------------------------------------------------------------
// init: dec_z=dec_c=0, c=0, prev=BOS, w0 = mask/len
// ---------------------------------------------------------------------------
__global__ __launch_bounds__(256) void init_kernel(const int* __restrict__ enc_len,
                                                   float* __restrict__ dec_z,
                                                   float* __restrict__ dec_c,
                                                   float* __restrict__ cbuf,
                                                   float* __restrict__ wbuf,
                                                   int* __restrict__ prev)
{
    int i = blockIdx.x * blockDim.x + threadIdx.x;
    if (i < B * H) { dec_z[i] = 0.f; dec_c[i] = 0.f; }
    if (i < B * AO) cbuf[i] = 0.f;
    if (i < B) prev[i] = BOS;
    if (i < B * T) {
        int b = i / T, t = i % T;
        int len = enc_len[b];
        wbuf[i] = (t < len) ? 1.f / (float)len : 0.f;
    }
}

// ---------------------------------------------------------------------------
// Generic tiled GEMM: C[M,N] = A[M,K] * W[N,K]^T (+bias) (+=C if accumulate)
// block = 16x16 threads, tile = (16*WPT)^2, TK = 32
// ---------------------------------------------------------------------------
template <int WPT>
__global__ __launch_bounds__(256) void gemm_xwT(const float* __restrict__ Ag, int lda,
                                                const float* __restrict__ Wg, int ldw,
                                                const float* __restrict__ bias,
                                                float* __restrict__ Cg, int ldc,
                                                int M, int N, int K, int accumulate)
{
    constexpr int TM = 16 * WPT;
    constexpr int TN = 16 * WPT;
    constexpr int TK = 32;
    __shared__ float As[TM][TK + 1];
    __shared__ float Ws[TN][TK + 1];

    int tx = threadIdx.x, ty = threadIdx.y;
    int tid = ty * 16 + tx;
    int m0 = blockIdx.y * TM, n0 = blockIdx.x * TN;

    float acc[WPT][WPT] = {};

    for (int k0 = 0; k0 < K; k0 += TK) {
        constexpr int LOADS = TM * TK / 256;
#pragma unroll
        for (int i = 0; i < LOADS; ++i) {
            int e = tid + i * 256;
            int r = e / TK, cidx = e % TK;
            int gk = k0 + cidx;
            int gm = m0 + r;
            As[r][cidx] = (gm < M && gk < K) ? Ag[(size_t)gm * lda + gk] : 0.f;
            int gn = n0 + r;
            Ws[r][cidx] = (gn < N && gk < K) ? Wg[(size_t)gn * ldw + gk] : 0.f;
        }
        __syncthreads();
#pragma unroll
        for (int kk = 0; kk < TK; ++kk) {
            float av[WPT], wv[WPT];
#pragma unroll
            for (int i = 0; i < WPT; ++i) { av[i] = As[ty * WPT + i][kk]; wv[i] = Ws[tx * WPT + i][kk]; }
#pragma unroll
            for (int i = 0; i < WPT; ++i)
#pragma unroll
                for (int j = 0; j < WPT; ++j) acc[i][j] += av[i] * wv[j];
        }
        __syncthreads();
    }

#pragma unroll
    for (int i = 0; i < WPT; ++i)
#pragma unroll
        for (int j = 0; j < WPT; ++j) {
            int gm = m0 + ty * WPT + i, gn = n0 + tx * WPT + j;
            if (gm < M && gn < N) {
                float v = acc[i][j] + (bias ? bias[gn] : 0.f);
                if (accumulate) v += Cg[(size_t)gm * ldc + gn];
                Cg[(size_t)gm * ldc + gn] = v;
            }
        }
}

// ---------------------------------------------------------------------------
// x = [embedding[prev], c]   (B x 1024)
// ---------------------------------------------------------------------------
__global__ __launch_bounds__(256) void build_x(const float* __restrict__ emb,
                                               const int* __restrict__ prev,
                                               const float* __restrict__ cbuf,
                                               float* __restrict__ x)
{
    int i = blockIdx.x * blockDim.x + threadIdx.x;
    if (i >= B * (E + AO)) return;
    int b = i >> 10, k = i & 1023;
    x[i] = (k < E) ? emb[(size_t)prev[b] * E + k] : cbuf[b * AO + (k - E)];
}

// y = [dec_z, cvec]  (B x 1024)
__global__ __launch_bounds__(256) void build_y(const float* __restrict__ dz,
                                               const float* __restrict__ cv,
                                               float* __restrict__ y)
{
    int i = blockIdx.x * blockDim.x + threadIdx.x;
    if (i >= B * (H + AO)) return;
    int b = i >> 10, k = i & 1023;
    y[i] = (k < H) ? dz[b * H + k] : cv[b * AO + (k - H)];
}

// ---------------------------------------------------------------------------
// LSTM cell update
// ---------------------------------------------------------------------------
__global__ __launch_bounds__(256) void lstm_update(const float* __restrict__ gates,
                                                   float* __restrict__ dec_z,
                                                   float* __restrict__ dec_c)
{
    int i = blockIdx.x * blockDim.x + threadIdx.x;
    if (i >= B * H) return;
    int b = i / H, h = i % H;
    const float* g = gates + (size_t)b * 4 * H;
    float ig = sigmoidf_(g[h]);
    float fg = sigmoidf_(g[H + h]);
    float gg = tanhf(g[2 * H + h]);
    float og = sigmoidf_(g[3 * H + h]);
    float cN = fg * dec_c[i] + ig * gg;
    dec_c[i] = cN;
    dec_z[i] = og * tanhf(cN);
}

// ---------------------------------------------------------------------------
// Attention: conv(w) -> e = tanh(pre_enc + dec_t + att_conv) . W_g -> softmax
// one block per batch element, 256 threads
// ---------------------------------------------------------------------------
__global__ __launch_bounds__(256) void attention_kernel(const float* __restrict__ pre_enc,
                                                        float* __restrict__ w,
                                                        const float* __restrict__ conv_k,
                                                        const float* __restrict__ W_att,
                                                        const float* __restrict__ dec_t,
                                                        const float* __restrict__ W_g,
                                                        float* __restrict__ out_ws,
                                                        int step)
{
    int b = blockIdx.x;
    int tid = threadIdx.x;

    __shared__ float w_s[T];
    __shared__ float conv_s[T * CC];
    __shared__ float ck_s[CC * KW];
    __shared__ float watt_s[A * CC];
    __shared__ float dect_s[A];
    __shared__ float wg_s[A];
    __shared__ float e_s[T];
    __shared__ float red_s[256];

    for (int i = tid; i < T; i += 256) w_s[i] = w[b * T + i];
    for (int i = tid; i < CC * KW; i += 256) ck_s[i] = conv_k[i];
    for (int i = tid; i < A * CC; i += 256) watt_s[i] = W_att[i];
    for (int i = tid; i < A; i += 256) { dect_s[i] = dec_t[b * A + i]; wg_s[i] = W_g[i]; }
    __syncthreads();

    // 1D conv, cross-correlation, zero padding K on both sides
    for (int i = tid; i < T * CC; i += 256) {
        int t = i / CC, ch = i % CC;
        float s = 0.f;
        int k0 = (KK - t) > 0 ? (KK - t) : 0;
        int k1 = (T + KK - t) < KW ? (T + KK - t) : KW;
        for (int k = k0; k < k1; ++k) s += w_s[t + k - KK] * ck_s[ch * KW + k];
        conv_s[t * CC + ch] = s;
    }
    __syncthreads();

    // e[t] = sum_a tanh(pre_enc + dec_t + att_conv) * W_g[a]
    int wv = tid >> 6, lane = tid & 63;
    for (int t = wv; t < T; t += 4) {
        float partial = 0.f;
#pragma unroll
        for (int j = 0; j < 4; ++j) {
            int a = lane + 64 * j;
            float ac = 0.f;
#pragma unroll
            for (int ch = 0; ch < CC; ++ch) ac += conv_s[t * CC + ch] * watt_s[a * CC + ch];
            float val = tanhf(pre_enc[((size_t)b * T + t) * A + a] + dect_s[a] + ac);
            partial += val * wg_s[a];
        }
#pragma unroll
        for (int off = 32; off > 0; off >>= 1) partial += __shfl_down(partial, off, 64);
        if (lane == 0) e_s[t] = partial;
    }
    __syncthreads();

    // softmax over SCALING*e
    float m = -3.4e38f;
    for (int t = tid; t < T; t += 256) m = fmaxf(m, e_s[t]);
    red_s[tid] = m; __syncthreads();
    for (int s = 128; s > 0; s >>= 1) {
        if (tid < s) red_s[tid] = fmaxf(red_s[tid], red_s[tid + s]);
        __syncthreads();
    }
    m = red_s[0]; __syncthreads();

    float ssum = 0.f;
    for (int t = tid; t < T; t += 256) ssum += expf(SCALING * (e_s[t] - m));
    red_s[tid] = ssum; __syncthreads();
    for (int s = 128; s > 0; s >>= 1) {
        if (tid < s) red_s[tid] += red_s[tid + s];
        __syncthreads();
    }
    float inv = 1.f / red_s[0];
    for (int t = tid; t < T; t += 256) {
        float wn = expf(SCALING * (e_s[t] - m)) * inv;
        w[b * T + t] = wn;
        out_ws[((size_t)b * TD + step) * T + t] = wn;
    }
}

// ---------------------------------------------------------------------------
// ctx[b,d] = sum_t w[b,t] * enc_pad[b,t,d]
// grid = B * (ENC/256), block = 256
// ---------------------------------------------------------------------------
__global__ __launch_bounds__(256) void ctx_kernel(const float* __restrict__ enc_pad,
                                                  const float* __restrict__ w,
                                                  float* __restrict__ ctx)
{
    int b = blockIdx.x / (ENC / 256);
    int d = (blockIdx.x % (ENC / 256)) * 256 + threadIdx.x;
    __shared__ float w_s[T];
    for (int t = threadIdx.x; t < T; t += 256) w_s[t] = w[b * T + t];
    __syncthreads();
    float s = 0.f;
    const float* ep = enc_pad + (size_t)b * T * ENC + d;
    for (int t = 0; t < T; ++t) s += w_s[t] * ep[(size_t)t * ENC];
    ctx[b * ENC + d] = s;
}

// ---------------------------------------------------------------------------
// per-b: argmax (first index) + logsumexp of logits row; update prev, outputs
// ---------------------------------------------------------------------------
__global__ __launch_bounds__(256) void finalize_kernel(const float* __restrict__ logits,
                                                       int step,
                                                       int* __restrict__ prev,
                                                       float* __restrict__ out_preds,
                                                       float* __restrict__ out_ylp)
{
    int b = blockIdx.x, tid = threadIdx.x;
    const float* lg = logits + (size_t)b * TD * V + (size_t)step * V;
    __shared__ float rv[256];
    __shared__ int ri[256];

    float m = -3.4e38f; int mi = 0x7fffffff;
    for (int v = tid; v < V; v += 256) {
        float x = lg[v];
        if (x > m) { m = x; mi = v; }
    }
    rv[tid] = m; ri[tid] = mi; __syncthreads();
    for (int s = 128; s > 0; s >>= 1) {
        if (tid < s) {
            if (rv[tid + s] > rv[tid] || (rv[tid + s] == rv[tid] && ri[tid + s] < ri[tid])) {
                rv[tid] = rv[tid + s]; ri[tid] = ri[tid + s];
            }
        }
        __syncthreads();
    }
    m = rv[0]; mi = ri[0]; __syncthreads();

    float ssum = 0.f;
    for (int v = tid; v < V; v += 256) ssum += expf(lg[v] - m);
    rv[tid] = ssum; __syncthreads();
    for (int s = 128; s > 0; s >>= 1) {
        if (tid < s) rv[tid] += rv[tid + s];
        __syncthreads();
    }
    if (tid == 0) {
        prev[b] = mi;
        out_preds[b * TD + step] = (float)mi;
        out_ylp[b * TD + step] = -logf(rv[0]);   // lg[mi]-m-log(sum) with lg[mi]==m
    }
}

// ---------------------------------------------------------------------------
extern "C" void kernel_launch(void* const* d_in, const int* in_sizes, int n_in,
                              void* d_out, int out_size, void* d_ws, size_t ws_size,
                              hipStream_t stream)
{
    const float* enc_pad   = (const float*)d_in[0];
    const int*   enc_len   = (const int*)d_in[1];
    const float* embedding = (const float*)d_in[2];
    const float* W_ih      = (const float*)d_in[3];
    const float* b_ih      = (const float*)d_in[4];
    const float* W_hh      = (const float*)d_in[5];
    const float* b_hh      = (const float*)d_in[6];
    const float* W_enc     = (const float*)d_in[7];
    const float* b_enc     = (const float*)d_in[8];
    const float* W_dec     = (const float*)d_in[9];
    const float* W_att     = (const float*)d_in[10];
    const float* conv_k    = (const float*)d_in[11];
    const float* W_g       = (const float*)d_in[12];
    const float* W_o       = (const float*)d_in[13];
    const float* b_o       = (const float*)d_in[14];
    const float* W_out     = (const float*)d_in[15];
    const float* b_out     = (const float*)d_in[16];

    float* out_logits = (float*)d_out;                       // [B,TD,V]
    float* out_ylp    = out_logits + (size_t)B * TD * V;     // [B,TD]
    float* out_preds  = out_ylp + B * TD;                    // [B,TD]
    float* out_ws     = out_preds + B * TD;                  // [B,TD,T]

    float* wsf     = (float*)d_ws;
    float* pre_enc = wsf;                        // B*T*A
    float* dec_z   = pre_enc + (size_t)B * T * A;
    float* dec_c   = dec_z + B * H;
    float* cbuf    = dec_c + B * H;              // B*AO
    float* wbuf    = cbuf + B * AO;              // B*T
    float* xbuf    = wbuf + B * T;               // B*1024
    float* gates   = xbuf + B * (E + AO);        // B*4H
    float* dect    = gates + B * 4 * H;          // B*A
    float* ctx     = dect + B * A;               // B*ENC
    float* ybuf    = ctx + B * ENC;              // B*1024
    int*   prev    = (int*)(ybuf + B * (H + AO));

    dim3 blk(16, 16);

    init_kernel<<<(B * H + 255) / 256, 256, 0, stream>>>(enc_len, dec_z, dec_c, cbuf, wbuf, prev);

    // pre_enc = enc_pad @ W_enc^T + b_enc : M=B*T, N=A, K=ENC (WPT=4 -> 64x64 tiles)
    gemm_xwT<4><<<dim3((A + 63) / 64, (B * T + 63) / 64), blk, 0, stream>>>(
        enc_pad, ENC, W_enc, ENC, b_enc, pre_enc, A, B * T, A, ENC, 0);

    for (int s = 0; s < TD; ++s) {
        build_x<<<(B * (E + AO) + 255) / 256, 256, 0, stream>>>(embedding, prev, cbuf, xbuf);

        // gates = x@W_ih^T + b_ih ; gates += dec_z@W_hh^T + b_hh
        gemm_xwT<2><<<dim3((4 * H + 31) / 32, 1), blk, 0, stream>>>(
            xbuf, E + AO, W_ih, E + AO, b_ih, gates, 4 * H, B, 4 * H, E + AO, 0);
        gemm_xwT<2><<<dim3((4 * H + 31) / 32, 1), blk, 0, stream>>>(
            dec_z, H, W_hh, H, b_hh, gates, 4 * H, B, 4 * H, H, 1);

        lstm_update<<<(B * H + 255) / 256, 256, 0, stream>>>(gates, dec_z, dec_c);

        // dec_t = dec_z @ W_dec^T : M=B, N=A, K=H
        gemm_xwT<2><<<dim3((A + 31) / 32, 1), blk, 0, stream>>>(
            dec_z, H, W_dec, H, nullptr, dect, A, B, A, H, 0);

        attention_kernel<<<B, 256, 0, stream>>>(pre_enc, wbuf, conv_k, W_att, dect, W_g, out_ws, s);

        ctx_kernel<<<B * (ENC / 256), 256, 0, stream>>>(enc_pad, wbuf, ctx);

        // cvec = ctx @ W_o^T + b_o : M=B, N=AO, K=ENC
        gemm_xwT<2><<<dim3((AO + 31) / 32, 1), blk, 0, stream>>>(
            ctx, ENC, W_o, ENC, b_o, cbuf, AO, B, AO, ENC, 0);

        build_y<<<(B * (H + AO) + 255) / 256, 256, 0, stream>>>(dec_z, cbuf, ybuf);

        // logits = y @ W_out^T + b_out : M=B, N=V, K=H+AO, written into d_out
        gemm_xwT<2><<<dim3((V + 31) / 32, 1), blk, 0, stream>>>(
            ybuf, H + AO, W_out, H + AO, b_out, out_logits + (size_t)s * V, TD * V,
            B, V, H + AO, 0);

        finalize_kernel<<<B, 256, 0, stream>>>(out_logits, s, prev, out_preds, out_ylp);
    }
}

// Round 2
// 16316.269 us; speedup vs baseline: 3.2414x; 3.2414x over previous
//
#include <hip/hip_runtime.h>
#include <math.h>

// Problem constants
#define NB   32      // batch
#define NT   300     // encoder frames
#define NE   1024    // encoder dim
#define NH   512     // hidden
#define NA   256     // attention dim
#define NC   10      // conv channels
#define NKW  201     // conv kernel width (2K+1), K=100
#define NV   10000   // vocab
#define NEMB 512     // embedding dim
#define NAO  512     // attention output dim
#define NTD  80      // decode steps
#define SCL  2.0f

__device__ __forceinline__ float sigf(float x){ return 1.f/(1.f+expf(-x)); }

// ---------------------------------------------------------------------------
// init: zbuf(dec_z)=0, dec_c=0, cvec_parts=0, prev=BOS, wbuf=w0(mask/len)
// ---------------------------------------------------------------------------
__global__ __launch_bounds__(256) void k_init(const int* __restrict__ enc_len,
    float* __restrict__ zbuf, float* __restrict__ dec_c, float* __restrict__ cp,
    float* __restrict__ wbuf, int* __restrict__ prev)
{
    int i = blockIdx.x*256 + threadIdx.x;           // 32768 threads
    if (i < NB*NH)   { zbuf[i]=0.f; dec_c[i]=0.f; }
    if (i < 2*NB*NAO)  cp[i]=0.f;
    if (i < NB*NT)   { int b=i/NT, t=i%NT; int len=enc_len[b];
                       wbuf[i] = (t<len)? 1.f/(float)len : 0.f; }
    if (i < NB)        prev[i]=1;                   // BOS
}

// ---------------------------------------------------------------------------
// Precompute pre_enc = enc_pad @ W_enc^T + b_enc.  M=9600,K=1024 exact tiles.
// 64x64 tile, KT=32, transposed LDS tiles for b128 fragment reads.
// ---------------------------------------------------------------------------
__global__ __launch_bounds__(256) void k_gemm_pre(const float* __restrict__ Ag,
    const float* __restrict__ Wg, const float* __restrict__ bias,
    float* __restrict__ Cg, int N)
{
    __shared__ float As[32][68];   // [kk][m]
    __shared__ float Bs[32][68];   // [kk][n]
    const int tid = threadIdx.x;
    const int m0 = blockIdx.y*64, n0 = blockIdx.x*64;
    const int r  = tid>>2, kg = (tid&3)*8;
    const int ty = tid>>4, tx = tid&15;
    float acc[4][4] = {};
    for (int k0 = 0; k0 < 1024; k0 += 32) {
        const float4 a0 = *(const float4*)(Ag + (size_t)(m0+r)*1024 + k0+kg);
        const float4 a1 = *(const float4*)(Ag + (size_t)(m0+r)*1024 + k0+kg+4);
        const float4 b0 = *(const float4*)(Wg + (size_t)(n0+r)*1024 + k0+kg);
        const float4 b1 = *(const float4*)(Wg + (size_t)(n0+r)*1024 + k0+kg+4);
        __syncthreads();
        As[kg+0][r]=a0.x; As[kg+1][r]=a0.y; As[kg+2][r]=a0.z; As[kg+3][r]=a0.w;
        As[kg+4][r]=a1.x; As[kg+5][r]=a1.y; As[kg+6][r]=a1.z; As[kg+7][r]=a1.w;
        Bs[kg+0][r]=b0.x; Bs[kg+1][r]=b0.y; Bs[kg+2][r]=b0.z; Bs[kg+3][r]=b0.w;
        Bs[kg+4][r]=b1.x; Bs[kg+5][r]=b1.y; Bs[kg+6][r]=b1.z; Bs[kg+7][r]=b1.w;
        __syncthreads();
        #pragma unroll
        for (int kk=0; kk<32; ++kk) {
            const float4 av = *(const float4*)&As[kk][ty*4];
            const float4 bv = *(const float4*)&Bs[kk][tx*4];
            const float a[4]={av.x,av.y,av.z,av.w};
            const float bb[4]={bv.x,bv.y,bv.z,bv.w};
            #pragma unroll
            for (int i=0;i<4;++i)
                #pragma unroll
                for (int j=0;j<4;++j) acc[i][j] += a[i]*bb[j];
        }
    }
    #pragma unroll
    for (int i=0;i<4;++i){
        const int m = m0 + ty*4 + i;
        #pragma unroll
        for (int j=0;j<4;++j)
            Cg[(size_t)m*N + n0 + tx*4 + j] = acc[i][j] + bias[n0+tx*4+j];
    }
}

// ---------------------------------------------------------------------------
// gates partials: gp[kp][b][n] = sum_{k in chunk} x[b][k]*Wcat[n][k]
// x = [emb[prev] (512) | cvec=cp0+cp1 (512) | dec_z (512)], Wcat = [W_ih|W_hh]
// grid (64, 4), 256 thr. Block: 32 n, all 32 b. Thread: 2b x 2n.
// ---------------------------------------------------------------------------
__global__ __launch_bounds__(256) void k_gates(const float* __restrict__ emb,
    const int* __restrict__ prev, const float* __restrict__ cp,
    const float* __restrict__ zbuf, const float* __restrict__ W_ih,
    const float* __restrict__ W_hh, float* __restrict__ gp)
{
    __shared__ float xt[32][68];
    const int tid = threadIdx.x;
    const int kp  = blockIdx.y;                    // 0..3, chunks of 384
    const int lane = tid&63, wv = tid>>6;
    const int bs = lane&15, nsl = lane>>4;
    const int n0 = blockIdx.x*32 + wv*8 + nsl*2;
    const int sb = tid>>3, sk = (tid&7)*8;
    const int pvs = prev[sb];
    const float* wih0 = W_ih + (size_t)n0*1024;
    const float* whh0 = W_hh + (size_t)n0*512;
    float a00=0.f,a01=0.f,a10=0.f,a11=0.f;
    for (int tile=0; tile<6; ++tile) {
        const int k0 = kp*384 + tile*64;
        const int gk = k0 + sk;
        float4 v0, v1;
        if (gk < 512) {
            const float4* p = (const float4*)(emb + (size_t)pvs*NEMB + gk);
            v0 = p[0]; v1 = p[1];
        } else if (gk < 1024) {
            const float4* p0 = (const float4*)(cp + sb*NAO + (gk-512));
            const float4* p1 = (const float4*)(cp + NB*NAO + sb*NAO + (gk-512));
            const float4 x0=p0[0], x1=p1[0], y0=p0[1], y1=p1[1];
            v0 = make_float4(x0.x+x1.x, x0.y+x1.y, x0.z+x1.z, x0.w+x1.w);
            v1 = make_float4(y0.x+y1.x, y0.y+y1.y, y0.z+y1.z, y0.w+y1.w);
        } else {
            const float4* p = (const float4*)(zbuf + sb*NH + (gk-1024));
            v0 = p[0]; v1 = p[1];
        }
        __syncthreads();
        *(float4*)&xt[sb][sk]   = v0;
        *(float4*)&xt[sb][sk+4] = v1;
        __syncthreads();
        const float* w0 = (k0 < 1024) ? wih0 + k0        : whh0 + (k0-1024);
        const float* w1 = (k0 < 1024) ? wih0 + 1024 + k0 : whh0 + 512 + (k0-1024);
        #pragma unroll
        for (int c=0;c<16;++c){
            const float4 xa = *(const float4*)&xt[bs][c*4];
            const float4 xb = *(const float4*)&xt[bs+16][c*4];
            const float4 wa = *(const float4*)(w0 + c*4);
            const float4 wb = *(const float4*)(w1 + c*4);
            a00 += xa.x*wa.x+xa.y*wa.y+xa.z*wa.z+xa.w*wa.w;
            a01 += xa.x*wb.x+xa.y*wb.y+xa.z*wb.z+xa.w*wb.w;
            a10 += xb.x*wa.x+xb.y*wa.y+xb.z*wa.z+xb.w*wa.w;
            a11 += xb.x*wb.x+xb.y*wb.y+xb.z*wb.z+xb.w*wb.w;
        }
    }
    float* g = gp + (size_t)(kp*NB)*2048;
    g[(size_t)bs*2048 + n0]        = a00;
    g[(size_t)bs*2048 + n0+1]      = a01;
    g[(size_t)(bs+16)*2048 + n0]   = a10;
    g[(size_t)(bs+16)*2048 + n0+1] = a11;
}

// ---------------------------------------------------------------------------
// LSTM combine: sum 4 gate parts + biases, update dec_c, write dec_z to zbuf
// ---------------------------------------------------------------------------
__global__ __launch_bounds__(256) void k_lstm(const float* __restrict__ gp,
    const float* __restrict__ b_ih, const float* __restrict__ b_hh,
    float* __restrict__ dec_c, float* __restrict__ zbuf)
{
    const int i = blockIdx.x*256 + threadIdx.x;    // 16384
    const int b = i>>9, h = i&511;
    float g[4];
    #pragma unroll
    for (int r=0;r<4;++r){
        float s = b_ih[r*512+h] + b_hh[r*512+h];
        #pragma unroll
        for (int kp=0;kp<4;++kp) s += gp[(size_t)(kp*NB+b)*2048 + r*512 + h];
        g[r]=s;
    }
    const float c = sigf(g[1])*dec_c[i] + sigf(g[0])*tanhf(g[2]);
    dec_c[i] = c;
    zbuf[i]  = sigf(g[3])*tanhf(c);
}

// ---------------------------------------------------------------------------
// dec_t partials: dp[kp][b][a] = sum_{k chunk} dec_z[b][k]*W_dec[a][k]
// grid (8, 2), 256 thr, thread 2b x 2n, global-direct.
// ---------------------------------------------------------------------------
__global__ __launch_bounds__(256) void k_dect(const float* __restrict__ zbuf,
    const float* __restrict__ W_dec, float* __restrict__ dp)
{
    const int tid=threadIdx.x, kp=blockIdx.y;
    const int lane=tid&63, wv=tid>>6, bs=lane&15, nsl=lane>>4;
    const int n0 = blockIdx.x*32 + wv*8 + nsl*2;
    const float* x0 = zbuf + bs*NH;
    const float* x1 = zbuf + (bs+16)*NH;
    const float* w0 = W_dec + (size_t)n0*NH;
    const float* w1 = w0 + NH;
    float a00=0.f,a01=0.f,a10=0.f,a11=0.f;
    const int kb = kp*256;
    #pragma unroll 8
    for (int c=0;c<64;++c){
        const int k = kb + c*4;
        const float4 xa = *(const float4*)(x0+k);
        const float4 xb = *(const float4*)(x1+k);
        const float4 wa = *(const float4*)(w0+k);
        const float4 wb = *(const float4*)(w1+k);
        a00 += xa.x*wa.x+xa.y*wa.y+xa.z*wa.z+xa.w*wa.w;
        a01 += xa.x*wb.x+xa.y*wb.y+xa.z*wb.z+xa.w*wb.w;
        a10 += xb.x*wa.x+xb.y*wa.y+xb.z*wa.z+xb.w*wa.w;
        a11 += xb.x*wb.x+xb.y*wb.y+xb.z*wb.z+xb.w*wb.w;
    }
    dp[(size_t)(kp*NB+bs)*NA + n0]        = a00;
    dp[(size_t)(kp*NB+bs)*NA + n0+1]      = a01;
    dp[(size_t)(kp*NB+bs+16)*NA + n0]     = a10;
    dp[(size_t)(kp*NB+bs+16)*NA + n0+1]   = a11;
}

// ---------------------------------------------------------------------------
// attention scores e[b][t]: conv(w_prev) -> tanh(pre_enc+dec_t+att_conv).W_g
// grid (5 t-chunks of 60, 32 b), 256 thr
// ---------------------------------------------------------------------------
__global__ __launch_bounds__(256) void k_escore(const float* __restrict__ pre_enc,
    const float* __restrict__ wprev, const float* __restrict__ ck,
    const float* __restrict__ W_att, const float* __restrict__ dp,
    const float* __restrict__ W_g, float* __restrict__ ebuf)
{
    __shared__ float w_h[260];
    __shared__ float ck_s[NC*NKW];     // 2010
    __shared__ float wt_s[NA*NC];      // 2560
    __shared__ float dt_s[NA];
    __shared__ float wg_s[NA];
    __shared__ float cv_s[60*NC];      // 600
    __shared__ float ep_s[60][4];
    const int tid = threadIdx.x;
    const int b = blockIdx.y, t0 = blockIdx.x*60;
    for (int i=tid;i<260;i+=256){ const int gt=t0-100+i;
        w_h[i] = (gt>=0 && gt<NT)? wprev[b*NT+gt] : 0.f; }
    for (int i=tid;i<NC*NKW;i+=256) ck_s[i]=ck[i];
    for (int i=tid;i<NA*NC;i+=256)  wt_s[i]=W_att[i];
    dt_s[tid&255] = dp[b*NA+(tid&255)] + dp[NB*NA + b*NA+(tid&255)];
    wg_s[tid&255] = W_g[tid&255];
    __syncthreads();
    for (int i=tid;i<60*NC;i+=256){
        const int tl=i/NC, ch=i%NC;
        float s=0.f;
        const float* wp  = &w_h[tl];
        const float* ckp = &ck_s[ch*NKW];
        for (int k=0;k<NKW;++k) s += wp[k]*ckp[k];
        cv_s[i]=s;
    }
    __syncthreads();
    const int tq = tid&3, tl = tid>>2;
    if (tl < 60) {
        float cv[NC];
        #pragma unroll
        for (int ch=0;ch<NC;++ch) cv[ch]=cv_s[tl*NC+ch];
        const float* pe = pre_enc + (size_t)(b*NT + t0 + tl)*NA;
        float part=0.f;
        for (int i=0;i<64;++i){
            const int aa = tq + 4*i;               // interleaved: bank-spread
            float attc = 0.f;
            #pragma unroll
            for (int ch=0;ch<NC;++ch) attc += cv[ch]*wt_s[aa*NC+ch];
            part += tanhf(pe[aa] + dt_s[aa] + attc) * wg_s[aa];
        }
        ep_s[tl][tq] = part;
    }
    __syncthreads();
    if (tid < 60)
        ebuf[b*NT + t0 + tid] = ep_s[tid][0]+ep_s[tid][1]+ep_s[tid][2]+ep_s[tid][3];
}

// ---------------------------------------------------------------------------
// softmax (recomputed per block) + ctx[b][d] = sum_t w[b,t]*enc_pad[b,t,d]
// grid (4 d-chunks of 256, 32 b); block x==0 also writes wbuf + out_ws
// ---------------------------------------------------------------------------
__global__ __launch_bounds__(256) void k_ctx(const float* __restrict__ ebuf,
    const float* __restrict__ enc_pad, float* __restrict__ ctx,
    float* __restrict__ wbuf, float* __restrict__ out_ws, int step)
{
    __shared__ float es[NT], wsm[NT], red[256];
    const int tid=threadIdx.x, b=blockIdx.y, d0=blockIdx.x*256;
    for (int t=tid;t<NT;t+=256) es[t]=ebuf[b*NT+t];
    __syncthreads();
    float m=-3.4e38f;
    for (int t=tid;t<NT;t+=256) m=fmaxf(m,es[t]);
    red[tid]=m; __syncthreads();
    for (int s=128;s>0;s>>=1){ if(tid<s) red[tid]=fmaxf(red[tid],red[tid+s]); __syncthreads(); }
    m=red[0]; __syncthreads();
    float ss=0.f;
    for (int t=tid;t<NT;t+=256) ss+=expf(SCL*(es[t]-m));
    red[tid]=ss; __syncthreads();
    for (int s=128;s>0;s>>=1){ if(tid<s) red[tid]+=red[tid+s]; __syncthreads(); }
    const float inv = 1.f/red[0];
    for (int t=tid;t<NT;t+=256){
        const float w = expf(SCL*(es[t]-m))*inv;
        wsm[t]=w;
        if (blockIdx.x==0){ wbuf[b*NT+t]=w; out_ws[((size_t)b*NTD+step)*NT+t]=w; }
    }
    __syncthreads();
    const float* ep = enc_pad + (size_t)b*NT*NE + d0 + tid;
    float acc=0.f;
    #pragma unroll 4
    for (int t=0;t<NT;++t) acc += wsm[t]*ep[(size_t)t*NE];
    ctx[b*NE + d0 + tid] = acc;
}

// ---------------------------------------------------------------------------
// cvec partials: cp[kp][b][o] = sum_{k chunk} ctx[b][k]*W_o[o][k] (+b_o in kp0)
// grid (16, 2), 256 thr, thread 2b x 2n, global-direct.
// ---------------------------------------------------------------------------
__global__ __launch_bounds__(256) void k_cvec(const float* __restrict__ ctx,
    const float* __restrict__ W_o, const float* __restrict__ b_o,
    float* __restrict__ cp)
{
    const int tid=threadIdx.x, kp=blockIdx.y;
    const int lane=tid&63, wv=tid>>6, bs=lane&15, nsl=lane>>4;
    const int n0 = blockIdx.x*32 + wv*8 + nsl*2;
    const float* x0 = ctx + bs*NE;
    const float* x1 = ctx + (bs+16)*NE;
    const float* w0 = W_o + (size_t)n0*NE;
    const float* w1 = w0 + NE;
    float a00=0.f,a01=0.f,a10=0.f,a11=0.f;
    const int kb = kp*512;
    #pragma unroll 8
    for (int c=0;c<128;++c){
        const int k = kb + c*4;
        const float4 xa = *(const float4*)(x0+k);
        const float4 xb = *(const float4*)(x1+k);
        const float4 wa = *(const float4*)(w0+k);
        const float4 wb = *(const float4*)(w1+k);
        a00 += xa.x*wa.x+xa.y*wa.y+xa.z*wa.z+xa.w*wa.w;
        a01 += xa.x*wb.x+xa.y*wb.y+xa.z*wb.z+xa.w*wb.w;
        a10 += xb.x*wa.x+xb.y*wa.y+xb.z*wa.z+xb.w*wa.w;
        a11 += xb.x*wb.x+xb.y*wb.y+xb.z*wb.z+xb.w*wb.w;
    }
    const float bo0 = (kp==0)? b_o[n0]   : 0.f;
    const float bo1 = (kp==0)? b_o[n0+1] : 0.f;
    cp[(size_t)(kp*NB+bs)*NAO + n0]        = a00 + bo0;
    cp[(size_t)(kp*NB+bs)*NAO + n0+1]      = a01 + bo1;
    cp[(size_t)(kp*NB+bs+16)*NAO + n0]     = a10 + bo0;
    cp[(size_t)(kp*NB+bs+16)*NAO + n0+1]   = a11 + bo1;
}

// ---------------------------------------------------------------------------
// logits partials: lp[kp][b][v] = sum_{k chunk} y[b][k]*W_out[v][k]
// y = [dec_z (512) | cvec = cp0+cp1 (512)].  grid (313, 2), 256 thr.
// ---------------------------------------------------------------------------
__global__ __launch_bounds__(256) void k_logits(const float* __restrict__ zbuf,
    const float* __restrict__ cp, const float* __restrict__ W_out,
    float* __restrict__ lp)
{
    __shared__ float xt[32][68];
    const int tid=threadIdx.x, kp=blockIdx.y;
    const int lane=tid&63, wv=tid>>6, bs=lane&15, nsl=lane>>4;
    const int n0 = blockIdx.x*32 + wv*8 + nsl*2;
    const int rn0 = (n0   < NV)? n0   : NV-1;
    const int rn1 = (n0+1 < NV)? n0+1 : NV-1;
    const float* w0 = W_out + (size_t)rn0*1024;
    const float* w1 = W_out + (size_t)rn1*1024;
    const int sb = tid>>3, sk = (tid&7)*8;
    float a00=0.f,a01=0.f,a10=0.f,a11=0.f;
    for (int tile=0; tile<8; ++tile) {
        const int k0 = kp*512 + tile*64;
        const int gk = k0 + sk;
        float4 v0, v1;
        if (gk < 512) {
            const float4* p = (const float4*)(zbuf + sb*NH + gk);
            v0 = p[0]; v1 = p[1];
        } else {
            const float4* p0 = (const float4*)(cp + sb*NAO + (gk-512));
            const float4* p1 = (const float4*)(cp + NB*NAO + sb*NAO + (gk-512));
            const float4 x0=p0[0], x1=p1[0], y0=p0[1], y1=p1[1];
            v0 = make_float4(x0.x+x1.x, x0.y+x1.y, x0.z+x1.z, x0.w+x1.w);
            v1 = make_float4(y0.x+y1.x, y0.y+y1.y, y0.z+y1.z, y0.w+y1.w);
        }
        __syncthreads();
        *(float4*)&xt[sb][sk]   = v0;
        *(float4*)&xt[sb][sk+4] = v1;
        __syncthreads();
        #pragma unroll
        for (int c=0;c<16;++c){
            const float4 xa = *(const float4*)&xt[bs][c*4];
            const float4 xb = *(const float4*)&xt[bs+16][c*4];
            const float4 wa = *(const float4*)(w0 + k0 + c*4);
            const float4 wb = *(const float4*)(w1 + k0 + c*4);
            a00 += xa.x*wa.x+xa.y*wa.y+xa.z*wa.z+xa.w*wa.w;
            a01 += xa.x*wb.x+xa.y*wb.y+xa.z*wb.z+xa.w*wb.w;
            a10 += xb.x*wa.x+xb.y*wa.y+xb.z*wa.z+xb.w*wa.w;
            a11 += xb.x*wb.x+xb.y*wb.y+xb.z*wb.z+xb.w*wb.w;
        }
    }
    if (n0 < NV){
        lp[(size_t)(kp*NB+bs)*NV + n0]    = a00;
        lp[(size_t)(kp*NB+bs+16)*NV + n0] = a10;
    }
    if (n0+1 < NV){
        lp[(size_t)(kp*NB+bs)*NV + n0+1]    = a01;
        lp[(size_t)(kp*NB+bs+16)*NV + n0+1] = a11;
    }
}

// ---------------------------------------------------------------------------
// finalize: logits = lp0+lp1+b_out -> d_out; argmax (first-idx) + logsumexp
// ---------------------------------------------------------------------------
__global__ __launch_bounds__(256) void k_fin(const float* __restrict__ lp,
    const float* __restrict__ b_out, int step, float* __restrict__ out_logits,
    int* __restrict__ prev, float* __restrict__ out_preds, float* __restrict__ out_ylp)
{
    __shared__ float rv[256];
    __shared__ int   ri[256];
    const int b=blockIdx.x, tid=threadIdx.x;
    const float* p0 = lp + (size_t)b*NV;
    const float* p1 = lp + (size_t)(NB+b)*NV;
    float* dst = out_logits + ((size_t)b*NTD + step)*NV;
    float m=-3.4e38f; int mi=NV;
    for (int v=tid; v<NV; v+=256){
        const float l = p0[v]+p1[v]+b_out[v];
        dst[v]=l;
        if (l>m){ m=l; mi=v; }
    }
    rv[tid]=m; ri[tid]=mi; __syncthreads();
    for (int s=128;s>0;s>>=1){
        if (tid<s){
            if (rv[tid+s]>rv[tid] || (rv[tid+s]==rv[tid] && ri[tid+s]<ri[tid])){
                rv[tid]=rv[tid+s]; ri[tid]=ri[tid+s];
            }
        }
        __syncthreads();
    }
    m=rv[0]; mi=ri[0]; __syncthreads();
    float ss=0.f;
    for (int v=tid; v<NV; v+=256) ss += expf(dst[v]-m);
    rv[tid]=ss; __syncthreads();
    for (int s=128;s>0;s>>=1){ if(tid<s) rv[tid]+=rv[tid+s]; __syncthreads(); }
    if (tid==0){
        prev[b]=mi;
        out_preds[b*NTD+step]=(float)mi;
        out_ylp[b*NTD+step]=-logf(rv[0]);
    }
}

// ---------------------------------------------------------------------------
extern "C" void kernel_launch(void* const* d_in, const int* in_sizes, int n_in,
                              void* d_out, int out_size, void* d_ws, size_t ws_size,
                              hipStream_t stream)
{
    const float* enc_pad   = (const float*)d_in[0];
    const int*   enc_len   = (const int*)d_in[1];
    const float* embedding = (const float*)d_in[2];
    const float* W_ih      = (const float*)d_in[3];
    const float* b_ih      = (const float*)d_in[4];
    const float* W_hh      = (const float*)d_in[5];
    const float* b_hh      = (const float*)d_in[6];
    const float* W_enc     = (const float*)d_in[7];
    const float* b_enc     = (const float*)d_in[8];
    const float* W_dec     = (const float*)d_in[9];
    const float* W_att     = (const float*)d_in[10];
    const float* conv_k    = (const float*)d_in[11];
    const float* W_g       = (const float*)d_in[12];
    const float* W_o       = (const float*)d_in[13];
    const float* b_o       = (const float*)d_in[14];
    const float* W_out     = (const float*)d_in[15];
    const float* b_out     = (const float*)d_in[16];

    float* out_logits = (float*)d_out;                        // [B,TD,V]
    float* out_ylp    = out_logits + (size_t)NB*NTD*NV;       // [B,TD]
    float* out_preds  = out_ylp + NB*NTD;                     // [B,TD]
    float* out_ws     = out_preds + NB*NTD;                   // [B,TD,T]

    float* f = (float*)d_ws;
    float* pre_enc = f;                                   // 9600*256
    float* zbuf    = pre_enc + (size_t)NB*NT*NA;          // 32*512  (dec_z)
    float* dec_c   = zbuf + NB*NH;                        // 32*512
    float* gp      = dec_c + NB*NH;                       // 4*32*2048
    float* dp      = gp + 4*NB*2048;                      // 2*32*256
    float* cp      = dp + 2*NB*NA;                        // 2*32*512
    float* ebuf    = cp + 2*NB*NAO;                       // 32*300
    float* wbuf    = ebuf + NB*NT;                        // 32*300
    float* ctx     = wbuf + NB*NT;                        // 32*1024
    float* lp      = ctx + NB*NE;                         // 2*32*10000
    int*   prev    = (int*)(lp + (size_t)2*NB*NV);        // 32

    k_init<<<128, 256, 0, stream>>>(enc_len, zbuf, dec_c, cp, wbuf, prev);
    k_gemm_pre<<<dim3(NA/64, NB*NT/64), 256, 0, stream>>>(enc_pad, W_enc, b_enc, pre_enc, NA);

    for (int s = 0; s < NTD; ++s) {
        k_gates <<<dim3(64,4),  256, 0, stream>>>(embedding, prev, cp, zbuf, W_ih, W_hh, gp);
        k_lstm  <<<64,          256, 0, stream>>>(gp, b_ih, b_hh, dec_c, zbuf);
        k_dect  <<<dim3(8,2),   256, 0, stream>>>(zbuf, W_dec, dp);
        k_escore<<<dim3(5,32),  256, 0, stream>>>(pre_enc, wbuf, conv_k, W_att, dp, W_g, ebuf);
        k_ctx   <<<dim3(4,32),  256, 0, stream>>>(ebuf, enc_pad, ctx, wbuf, out_ws, s);
        k_cvec  <<<dim3(16,2),  256, 0, stream>>>(ctx, W_o, b_o, cp);
        k_logits<<<dim3(313,2), 256, 0, stream>>>(zbuf, cp, W_out, lp);
        k_fin   <<<32,          256, 0, stream>>>(lp, b_out, s, out_logits, prev, out_preds, out_ylp);
    }
}